// Round 4
// baseline (384.619 us; speedup 1.0000x reference)
//
#include <hip/hip_runtime.h>
#include <hip/hip_bf16.h>
#include <math.h>

#define T_NCE 0.07f
#define EPSF 1e-7f

typedef unsigned int u32x4 __attribute__((ext_vector_type(4)));
typedef float f32x4 __attribute__((ext_vector_type(4)));

// ---------------- workspace layout (float units) ----------------
// [8]=cls [9]=rel [10]=act [11]=snico (zeroed by k_means block 0)
// WS_MEANS : 4*64*2048 per-batch channel SUMS (mean scale cancels in NCE)
// WS_DOTS/WS_NSQ : 2*64*150
// WS_PART  : C * 524288 partial sums (C chosen from ws_size)
#define WS_MEANS 32
#define MEANS_N (4 * 64 * 2048)
#define WS_DOTS (WS_MEANS + MEANS_N)
#define WS_NSQ  (WS_DOTS + 2 * 64 * 150)
#define WS_PART (WS_NSQ + 2 * 64 * 150)

__device__ __forceinline__ float bf2f(unsigned short h) {
    unsigned int u = ((unsigned int)h) << 16;
    float f;
    __builtin_memcpy(&f, &u, 4);
    return f;
}

__device__ __forceinline__ float ldf(const void* p, int i, int bf) {
    if (bf) return bf2f(((const unsigned short*)p)[i]);
    return ((const float*)p)[i];
}

// dtype probe: bf16 U(0,1) values have sign 0 and exponent in [90,126];
// f32 buffers seen as u16 pairs have random mantissa bits in the even slots.
__device__ __forceinline__ int probe_bf(const void* vs) {
    const unsigned short* u = (const unsigned short*)vs;
    int cnt = 0;
    for (int i = 0; i < 64; i++) {
        unsigned short h = u[2 * i];
        int e = (h >> 7) & 0xFF;
        int sgn = (h >> 15) & 1;
        if (!sgn && e >= 90 && e <= 126) cnt++;
    }
    return (cnt >= 56) ? 1 : 0;
}

__device__ __forceinline__ float block_reduce256(float v, float* sbuf) {
    int t = threadIdx.x;
    sbuf[t] = v;
    __syncthreads();
    for (int s = 128; s > 0; s >>= 1) {
        if (t < s) sbuf[t] += sbuf[t + s];
        __syncthreads();
    }
    float r = sbuf[0];
    __syncthreads();
    return r;
}

__device__ __forceinline__ float block_reduce_max256(float v, float* sbuf) {
    int t = threadIdx.x;
    sbuf[t] = v;
    __syncthreads();
    for (int s = 128; s > 0; s >>= 1) {
        if (t < s) sbuf[t] = fmaxf(sbuf[t], sbuf[t + s]);
        __syncthreads();
    }
    float r = sbuf[0];
    __syncthreads();
    return r;
}

// ---------------- kernel 1: per-batch channel partial sums ------------------
// grid 256*C = arr(4)*b(64)*chunk(C); block 256, 8 channels/thread,
// 5 independent loads in flight per thread (MLP).
__global__ void k_means(const void* HA, const void* EA, const void* HB, const void* EB,
                        const void* vs, float* ws, int C) {
    int bf = probe_bf(vs);
    int bi = blockIdx.x;
    if (bi == 0 && threadIdx.x == 0) {
        ws[8] = 0.f; ws[9] = 0.f; ws[10] = 0.f; ws[11] = 0.f;
    }
    int chunk = bi % C;
    int b = (bi / C) & 63;
    int arr = bi / (64 * C);
    const void* src = (arr == 0) ? HA : (arr == 1) ? EA : (arr == 2) ? HB : EB;
    int rows = 150 / C;
    int j0 = chunk * rows;
    int c0 = threadIdx.x * 8;
    float acc[8];
#pragma unroll
    for (int k = 0; k < 8; k++) acc[k] = 0.f;

    if (bf) {
        const unsigned short* p = (const unsigned short*)src;
        for (int jj = 0; jj < rows; jj += 5) {
            u32x4 r[5];
#pragma unroll
            for (int u = 0; u < 5; u++)
                r[u] = __builtin_nontemporal_load(
                    (const u32x4*)(p + ((size_t)(b * 150 + j0 + jj + u) * 2048 + c0)));
#pragma unroll
            for (int u = 0; u < 5; u++) {
                unsigned short hs[8];
                __builtin_memcpy(hs, &r[u], 16);
#pragma unroll
                for (int k = 0; k < 8; k++) acc[k] += bf2f(hs[k]);
            }
        }
    } else {
        const float* p = (const float*)src;
        for (int jj = 0; jj < rows; jj += 5) {
            f32x4 ra[5], rb[5];
#pragma unroll
            for (int u = 0; u < 5; u++) {
                const f32x4* q = (const f32x4*)(p + ((size_t)(b * 150 + j0 + jj + u) * 2048 + c0));
                ra[u] = __builtin_nontemporal_load(q);
                rb[u] = __builtin_nontemporal_load(q + 1);
            }
#pragma unroll
            for (int u = 0; u < 5; u++) {
#pragma unroll
                for (int k = 0; k < 4; k++) {
                    acc[k] += ra[u][k];
                    acc[4 + k] += rb[u][k];
                }
            }
        }
    }
    float* dst = (C == 1) ? (ws + WS_MEANS + (size_t)(arr * 64 + b) * 2048 + c0)
                          : (ws + WS_PART + (size_t)chunk * MEANS_N + (size_t)(arr * 64 + b) * 2048 + c0);
    f32x4 o0 = {acc[0], acc[1], acc[2], acc[3]};
    f32x4 o1 = {acc[4], acc[5], acc[6], acc[7]};
    *(f32x4*)dst = o0;
    *(f32x4*)(dst + 4) = o1;
}

// ---------------- kernel 2: fold C partials into WS_MEANS -------------------
__global__ void k_reduce(float* ws, int C) {
    int gid = blockIdx.x * 256 + threadIdx.x;  // 512*256 = 131072 float4s
    f32x4 s = {0.f, 0.f, 0.f, 0.f};
    for (int c = 0; c < C; c++) {
        f32x4 v = ((const f32x4*)(ws + WS_PART + (size_t)c * MEANS_N))[gid];
        s += v;
    }
    ((f32x4*)(ws + WS_MEANS))[gid] = s;
}

// ---------------- kernel 3: raw dots q.neg_row + row sumsq ------------------
// grid 1920 = which(2)*b(64)*chunk(15 of 10 rows); block 256 = 4 waves.
// q held in registers per lane (32 floats); no LDS, no barriers.
__global__ void k_dots(const void* EA, const void* EB, const void* vs, float* ws) {
    int bf = probe_bf(vs);
    int bi = blockIdx.x;
    int which = bi / 960;
    int rem = bi % 960;
    int b = rem / 15;
    int chunk = rem % 15;
    const float* q = ws + WS_MEANS + (size_t)((which == 0 ? 0 : 2) * 64 + b) * 2048;
    int lane = threadIdx.x & 63;
    int wid = threadIdx.x >> 6;
    float qreg[32];
#pragma unroll
    for (int it = 0; it < 4; it++) {
        f32x4 a = *(const f32x4*)(q + it * 512 + lane * 8);
        f32x4 c = *(const f32x4*)(q + it * 512 + lane * 8 + 4);
#pragma unroll
        for (int k = 0; k < 4; k++) {
            qreg[it * 8 + k] = a[k];
            qreg[it * 8 + 4 + k] = c[k];
        }
    }
    const void* neg = (which == 0) ? EB : EA;
    for (int j = chunk * 10 + wid; j < chunk * 10 + 10; j += 4) {
        size_t base = (size_t)(b * 150 + j) * 2048;
        float dot = 0.f, nsq = 0.f;
        if (bf) {
            const unsigned short* p = (const unsigned short*)neg;
            u32x4 r[4];
#pragma unroll
            for (int it = 0; it < 4; it++)
                r[it] = __builtin_nontemporal_load(
                    (const u32x4*)(p + base + it * 512 + lane * 8));
#pragma unroll
            for (int it = 0; it < 4; it++) {
                unsigned short hs[8];
                __builtin_memcpy(hs, &r[it], 16);
#pragma unroll
                for (int k = 0; k < 8; k++) {
                    float x = bf2f(hs[k]);
                    dot += x * qreg[it * 8 + k];
                    nsq += x * x;
                }
            }
        } else {
            const float* p = (const float*)neg;
#pragma unroll
            for (int it = 0; it < 4; it++) {
                const f32x4* qq = (const f32x4*)(p + base + it * 512 + lane * 8);
                f32x4 a = __builtin_nontemporal_load(qq);
                f32x4 c = __builtin_nontemporal_load(qq + 1);
#pragma unroll
                for (int k = 0; k < 4; k++) {
                    dot += a[k] * qreg[it * 8 + k];
                    nsq += a[k] * a[k];
                    dot += c[k] * qreg[it * 8 + 4 + k];
                    nsq += c[k] * c[k];
                }
            }
        }
        for (int s = 32; s > 0; s >>= 1) {
            dot += __shfl_down(dot, s);
            nsq += __shfl_down(nsq, s);
        }
        if (lane == 0) {
            ws[WS_DOTS + (which * 64 + b) * 150 + j] = dot;
            ws[WS_NSQ + (which * 64 + b) * 150 + j] = nsq;
        }
    }
}

// ---------------- kernel 4: fused cls + rel + act ---------------------------
__global__ void k_small(const void* vs, const void* label,
                        const void* res, const void* red,
                        const void* a0, const void* a2, float* ws) {
    int bf = probe_bf(vs);
    __shared__ float sbuf[256];
    __shared__ float rowsum[64];
    __shared__ float sa0[64 * 40];
    __shared__ float sa2[64 * 40];
    int t = threadIdx.x;
    int bi = blockIdx.x;

    if (bi == 0) {
        if (t < 64) {
            float s = 0.f;
            for (int c = 0; c < 20; c++) s += ldf(label, t * 20 + c, bf);
            rowsum[t] = s;
        }
        __syncthreads();
        float local = 0.f;
        for (int i = t; i < 1280; i += 256) {
            int b = i / 20;
            float lab = ldf(label, i, bf) / rowsum[b];
            float v = ldf(vs, i, bf);
            v = fminf(fmaxf(v, EPSF), 1.f - EPSF);
            local += lab * logf(v) + (1.f - lab) * log1pf(-v);
        }
        float s = block_reduce256(local, sbuf);
        if (t == 0) ws[8] = -s / 1280.f;
    } else if (bi <= 32) {
        int base = (bi - 1) * 256 + t;
        int stride = 32 * 256;
        float lrel = 0.f;
        for (int i = base; i < 96000; i += stride) {
            float sv = ldf(res, i, bf);
            float dv = ldf(red, i, bf);
            lrel += (1.f - sv) * (1.f - sv) + dv * dv;
        }
        float s = block_reduce256(lrel, sbuf);
        if (t == 0) atomicAdd(&ws[9], s * (1.f / 96000.f));
        float lact = 0.f;
        for (int i = base; i < 48000; i += stride) {
            float x = ldf(a0, i, bf) - ldf(a2, i, bf);
            lact += x * x;
        }
        s = block_reduce256(lact, sbuf);
        if (t == 0) atomicAdd(&ws[10], s * (0.1f / 64.f));
    } else {
        int abi = bi - 33;
        int B0 = abi * 256;
        int B1 = min(B0 + 255, 8249);
        int tmin = B0 / 11, tmax = B1 / 11;
        int lo = max(0, tmin - 6);
        int hi = min(749, tmax + 5);
        int ncol = hi - lo + 1;  // <= 36
        int total = 64 * ncol;
        for (int i = t; i < total; i += 256) {
            int b = i / ncol;
            int col = i % ncol;
            sa0[i] = ldf(a0, b * 750 + lo + col, bf);
            sa2[i] = ldf(a2, b * 750 + lo + col, bf);
        }
        __syncthreads();
        int id = B0 + t;
        float val = 0.f;
        if (id < 8250) {
            int tt = id / 11;
            int d = id % 11;
            int c = min(max(tt + d - 6, 0), 749);
            int ct = tt - lo, cc = c - lo;
            float wsum = 0.f, asum = 0.f;
            for (int b = 0; b < 64; b++) {
                float x = sa0[b * ncol + ct];
                float y = sa0[b * ncol + cc];
                wsum += (x - y) * (x - y);
                float p = sa2[b * ncol + ct];
                float q = sa2[b * ncol + cc];
                asum += fabsf(p - q);
            }
            val = __expf(-0.5f * wsum) * (asum * (1.f / 64.f));
        }
        float s = block_reduce256(val, sbuf);
        if (t == 0) atomicAdd(&ws[10], s);
    }
}

// ---------------- kernel 5: NCE norms + logsumexp per (which,b) -------------
__global__ void k_nce(const void* att, const void* vs, float* ws) {
    int bf = probe_bf(vs);
    __shared__ float sbuf[256];
    int t = threadIdx.x;
    int w = blockIdx.x >> 6;
    int b = blockIdx.x & 63;
    const float* qv = ws + WS_MEANS + (size_t)((w == 0 ? 0 : 2) * 64 + b) * 2048;
    const float* kv = ws + WS_MEANS + (size_t)((w == 0 ? 1 : 3) * 64 + b) * 2048;
    float p0 = 0.f, p1 = 0.f, p2 = 0.f;
    for (int c = t; c < 2048; c += 256) {
        float qa = qv[c], ka = kv[c];
        p0 += qa * qa; p1 += ka * ka; p2 += qa * ka;
    }
    float nq = block_reduce256(p0, sbuf);
    float nk = block_reduce256(p1, sbuf);
    float dd = block_reduce256(p2, sbuf);
    float invq = rsqrtf(nq);
    float lpos = dd * invq * rsqrtf(nk) * (1.f / T_NCE);
    float lg = -INFINITY;
    if (t < 150) {
        float raw = ws[WS_DOTS + (w * 64 + b) * 150 + t];
        float nn = ws[WS_NSQ + (w * 64 + b) * 150 + t];
        float a = ldf(att, b * 300 + w * 150 + t, bf);
        lg = a * raw * invq * rsqrtf(nn) * (1.f / T_NCE);
    }
    float m = block_reduce_max256(lg, sbuf);
    m = fmaxf(m, lpos);
    float ex = (t < 150) ? expf(lg - m) : 0.f;
    float ssum = block_reduce256(ex, sbuf) + expf(lpos - m);
    if (t == 0) {
        float loss = (m + logf(ssum)) - lpos;
        atomicAdd(&ws[11], loss * (1.f / 64.f));
    }
}

// ---------------- kernel 6: final combine -----------------------------------
__global__ void k_out(const void* vs, float* ws, void* out) {
    if (threadIdx.x == 0) {
        int bf = probe_bf(vs);
        float cls = ws[8], rel = ws[9], act = ws[10], snico = ws[11];
        float total = cls + 0.01f * snico + act + 0.1f * rel;
        if (bf) {
            __hip_bfloat16* o = (__hip_bfloat16*)out;
            o[0] = __float2bfloat16(total);
            o[1] = __float2bfloat16(cls);
            o[2] = __float2bfloat16(snico);
            o[3] = __float2bfloat16(act);
            o[4] = __float2bfloat16(rel);
        } else {
            float* o = (float*)out;
            o[0] = total; o[1] = cls; o[2] = snico; o[3] = act; o[4] = rel;
        }
    }
}

extern "C" void kernel_launch(void* const* d_in, const int* in_sizes, int n_in,
                              void* d_out, int out_size, void* d_ws, size_t ws_size,
                              hipStream_t stream) {
    const void* video_scores = d_in[0];
    const void* label = d_in[1];
    const void* HA = d_in[2];
    const void* EA = d_in[3];
    const void* HB = d_in[4];
    const void* EB = d_in[5];
    const void* re_s = d_in[6];
    const void* re_d = d_in[7];
    const void* actioness = d_in[8];
    const void* actioness_2 = d_in[9];
    const void* att = d_in[10];
    float* ws = (float*)d_ws;

    // pick chunk count C (must divide 150 with rows%5==0) from ws_size
    size_t avail = ws_size / 4;
    static const int cand[] = {10, 6, 5, 3, 2};
    int C = 1;
    for (int i = 0; i < 5; i++) {
        if ((size_t)WS_PART + (size_t)cand[i] * MEANS_N <= avail) { C = cand[i]; break; }
    }

    k_means<<<256 * C, 256, 0, stream>>>(HA, EA, HB, EB, video_scores, ws, C);
    if (C > 1) k_reduce<<<512, 256, 0, stream>>>(ws, C);
    k_dots<<<1920, 256, 0, stream>>>(EA, EB, video_scores, ws);
    k_small<<<66, 256, 0, stream>>>(video_scores, label, re_s, re_d,
                                    actioness, actioness_2, ws);
    k_nce<<<128, 256, 0, stream>>>(att, video_scores, ws);
    k_out<<<1, 64, 0, stream>>>(video_scores, ws, d_out);
}